// Round 12
// baseline (232.711 us; speedup 1.0000x reference)
//
#include <hip/hip_runtime.h>
#include <stdint.h>

typedef unsigned short u16;
typedef __bf16 bf16x8 __attribute__((ext_vector_type(8)));
typedef __bf16 bf16x2 __attribute__((ext_vector_type(2)));
typedef short s16x4 __attribute__((ext_vector_type(4)));
typedef float f32x4 __attribute__((ext_vector_type(4)));

typedef __attribute__((address_space(1))) void gvoid_t;
typedef __attribute__((address_space(3))) void lvoid_t;

struct alignas(16) U128 { uint32_t x, y, z, w; };
struct alignas(16) F128 { float x, y, z, w; };
struct alignas(8)  U64v { uint32_t x, y; };

__device__ __forceinline__ void gld16(const u16* g, u16* lds) {
  __builtin_amdgcn_global_load_lds((gvoid_t*)const_cast<u16*>(g),
                                   (lvoid_t*)lds, 16, 0, 0);
}

__device__ __forceinline__ u16 f2bf(float f) {
  uint32_t u = __builtin_bit_cast(uint32_t, f);
  u += 0x7FFFu + ((u >> 16) & 1u);   // RNE
  return (u16)(u >> 16);
}
__device__ __forceinline__ float bf2f(u16 h) {
  return __builtin_bit_cast(float, (uint32_t)h << 16);
}
__device__ __forceinline__ bf16x8 ldfrag(const u16* p) {
  U128 u = *reinterpret_cast<const U128*>(p);
  return __builtin_bit_cast(bf16x8, u);
}
// concat two 4x-bf16 halves into one 8x-bf16 MFMA fragment (no shuffles)
__device__ __forceinline__ bf16x8 cat8(U64v lo, U64v hi) {
  U128 u; u.x = lo.x; u.y = lo.y; u.z = hi.x; u.w = hi.y;
  return __builtin_bit_cast(bf16x8, u);
}
// pack two f32 -> bf16x2 dword via HW cvt (compiler emits v_cvt_pk_bf16_f32)
__device__ __forceinline__ uint32_t pkbf(float a, float b) {
  bf16x2 v;
  v[0] = (__bf16)a;
  v[1] = (__bf16)b;
  return __builtin_bit_cast(uint32_t, v);
}

// raw v_exp_f32 (exp2) — scores bounded (|s|<~10), no denormal concerns
__device__ __forceinline__ float EXP2(float x) { return __builtin_amdgcn_exp2f(x); }

// ---------------- fused prep: fp32->bf16 convert (x) + both weight transposes -------
__global__ void prep(const float* __restrict__ x, u16* __restrict__ Xb,
                     const float* __restrict__ Wq, u16* __restrict__ Wqkt,
                     const float* __restrict__ Wp, u16* __restrict__ Wpt) {
  const int id = blockIdx.x;
  const int tid = threadIdx.x;
  if (id < 6144) {
    int i = (id * 256 + tid) * 4;
    F128 v = *reinterpret_cast<const F128*>(x + i);
    U64v o;
    o.x = (uint32_t)f2bf(v.x) | ((uint32_t)f2bf(v.y) << 16);
    o.y = (uint32_t)f2bf(v.z) | ((uint32_t)f2bf(v.w) << 16);
    *reinterpret_cast<U64v*>(Xb + i) = o;
    return;
  }
  __shared__ float T[32][33];
  const float* W; u16* Wt; int K, N, n0, k0;
  if (id < 7872) {
    int e = id - 6144; W = Wq; Wt = Wqkt; K = 768; N = 2304;
    n0 = (e % 72) * 32; k0 = (e / 72) * 32;
  } else {
    int e = id - 7872; W = Wp; Wt = Wpt; K = 768; N = 768;
    n0 = (e % 24) * 32; k0 = (e / 24) * 32;
  }
#pragma unroll
  for (int i = 0; i < 4; ++i) {
    int e = i * 256 + tid, r = e >> 5, c = e & 31;
    T[r][c] = W[(size_t)(k0 + r) * N + n0 + c];
  }
  __syncthreads();
#pragma unroll
  for (int i = 0; i < 4; ++i) {
    int e = i * 256 + tid, r = e >> 5, c = e & 31;
    Wt[(size_t)(n0 + r) * K + k0 + c] = f2bf(T[c][r]);
  }
}

// =====================================================================================
// 8-wave GEMM, occupancy step 2: BM=BN=128, BK=32, 3-slot cyclic LDS (48 KB),
// 512 threads = 8 waves (4M x 2N, wave-tile 32x64, acc[2][4]),
// __launch_bounds__(512, 6) -> 3 blocks/CU = 24 waves/CU = 6 waves/SIMD
// (R7: 12 waves/CU = 73.5us; R11: 16 waves/CU ~= -15us total -> occupancy is the
// binding axis, schedule is not). VGPR cap @6 waves/SIMD ~= 85; K-loop live set
// ~= 70-80 -> should fit. Tripwire: spill => WRITE_SIZE balloons (R8 signature).
// Counted vmcnt(2): tile t+1's 2 loads/thread stay in flight across the barrier.
// =====================================================================================

#define GEMM_PIPE(A_, Bt_, KD_, NKT_)                                                \
  const int tid = threadIdx.x;                                                       \
  const int wave = tid >> 6, lane = tid & 63;                                        \
  const int quad = lane >> 4, l16 = lane & 15;                                       \
  const int m0 = by * 128, n0 = bx * 128;                                            \
  const int wm = wave & 3, wn = wave >> 2;    /* wave-tile: rows wm*32, cols wn*64 */ \
  f32x4 acc[2][4];                                                                   \
  _Pragma("unroll")                                                                  \
  for (int i = 0; i < 2; ++i)                                                        \
    _Pragma("unroll")                                                                \
    for (int j = 0; j < 4; ++j) acc[i][j] = (f32x4){0.f, 0.f, 0.f, 0.f};             \
  const int row0 = tid >> 2, kq0 = tid & 3;                                          \
  const u16* Ag0 = (A_) + (size_t)(m0 + row0) * (KD_) + kq0 * 8;                     \
  const u16* Bg0 = (Bt_) + (size_t)(n0 + row0) * (KD_) + kq0 * 8;                    \
  STG(0, 0);                                                                         \
  STG(1, 1);                                                                         \
  for (int t = 0; t < (NKT_); ++t) {                                                 \
    __builtin_amdgcn_sched_barrier(0);                                               \
    if (t < (NKT_) - 1) asm volatile("s_waitcnt vmcnt(2)" ::: "memory");             \
    else                asm volatile("s_waitcnt vmcnt(0)" ::: "memory");             \
    __builtin_amdgcn_sched_barrier(0);                                               \
    __builtin_amdgcn_s_barrier();                                                    \
    __builtin_amdgcn_sched_barrier(0);                                               \
    if (t + 2 < (NKT_)) STG(t + 2, (t + 2) % 3);                                     \
    const u16* Ab = Asl + (t % 3) * 4096;                                            \
    const u16* Bb = Bsl + (t % 3) * 4096;                                            \
    bf16x8 af[2], bfr[4];                                                            \
    _Pragma("unroll")                                                                \
    for (int rb = 0; rb < 2; ++rb)                                                   \
      af[rb] = ldfrag(&Ab[(wm * 32 + rb * 16 + l16) * 32 + quad * 8]);               \
    _Pragma("unroll")                                                                \
    for (int cb = 0; cb < 4; ++cb)                                                   \
      bfr[cb] = ldfrag(&Bb[(wn * 64 + cb * 16 + l16) * 32 + quad * 8]);              \
    __builtin_amdgcn_s_setprio(1);                                                   \
    _Pragma("unroll")                                                                \
    for (int rb = 0; rb < 2; ++rb)                                                   \
      _Pragma("unroll")                                                              \
      for (int cb = 0; cb < 4; ++cb)                                                 \
        acc[rb][cb] = __builtin_amdgcn_mfma_f32_16x16x32_bf16(                       \
            af[rb], bfr[cb], acc[rb][cb], 0, 0, 0);                                  \
    __builtin_amdgcn_s_setprio(0);                                                   \
  }

#define STG(t_, s_)                                                                  \
  do {                                                                               \
    const int k0_ = (t_) * 32;                                                       \
    gld16(Ag0 + k0_, &Asl[(s_) * 4096 + wave * 512]);                                \
    gld16(Bg0 + k0_, &Bsl[(s_) * 4096 + wave * 512]);                                \
  } while (0)

// ---------------- proj GEMM: C[M,N] = A[M,K] * Bt[N,K]^T + bias (f32 out) -----------
__global__ __launch_bounds__(512, 6)
void gemm_bt(const u16* __restrict__ A, const u16* __restrict__ Bt,
             const float* __restrict__ bias, float* __restrict__ C,
             int M, int N, int Karg) {
  (void)M; (void)Karg;
  __shared__ u16 Asl[3 * 4096];
  __shared__ u16 Bsl[3 * 4096];
  const int orig = blockIdx.y * 6 + blockIdx.x;
  const int swz = (orig % 8) * 48 + orig / 8;
  const int bx = swz % 6, by = swz / 6;
  GEMM_PIPE(A, Bt, 768, 24)
#pragma unroll
  for (int cb = 0; cb < 4; ++cb) {
    int col = n0 + wn * 64 + cb * 16 + l16;
    float bv = bias[col];
#pragma unroll
    for (int rb = 0; rb < 2; ++rb) {
#pragma unroll
      for (int r = 0; r < 4; ++r) {
        int row = m0 + wm * 32 + rb * 16 + quad * 4 + r;
        C[(size_t)row * N + col] = acc[rb][cb][r] + bv;
      }
    }
  }
}

// ---------------- fused QKV GEMM + bias + RoPE + scatter ----------------------------
// Grid (18,64), XCD-swizzled. bx: 0-5 Q, 6-11 K, 12-17 V. Wave col-span 64 == one
// head (wn*64). RoPE pair (d, d+32) lives in acc blocks (cb, cb+2) of the SAME lane.
// Q gets D^-0.5*log2e folded in (attn softmax runs in log2 domain).
// Q,K -> (B*H, N, D) bf16; V -> transposed (B*H, D, N) bf16 (4 tokens per 8B store).
__global__ __launch_bounds__(512, 6)
void gemm_qkv_rope(const u16* __restrict__ A, const u16* __restrict__ Bt,
                   const float* __restrict__ bias,
                   const float* __restrict__ cosT, const float* __restrict__ sinT,
                   const int* __restrict__ nsp,
                   u16* __restrict__ Qo, u16* __restrict__ Ko, u16* __restrict__ Vto) {
  __shared__ u16 Asl[3 * 4096];
  __shared__ u16 Bsl[3 * 4096];
  const int orig = blockIdx.y * 18 + blockIdx.x;
  const int swz = (orig % 8) * 144 + orig / 8;
  const int bx = swz % 18, by = swz / 18;
  GEMM_PIPE(A, Bt, 768, 24)

  const int sec = bx / 6;                  // 0=Q, 1=K, 2=V
  const int gcol0 = n0 + wn * 64;          // 64-aligned: one head per wave
  const int hh = (gcol0 >> 6) % 12;
  const int bb = m0 >> 11;
  const int nbase = m0 & 2047;
  const int bh = bb * 12 + hh;
  const int num_special = nsp[0];
  const float QS = 0.125f * 1.4426950408889634f;  // D^-0.5 * log2e

  if (sec < 2) {
    u16* outp = sec ? Ko : Qo;
    const float qs = sec ? 1.0f : QS;
#pragma unroll
    for (int cbp = 0; cbp < 2; ++cbp) {
      const int d1 = cbp * 16 + l16;
      const int d2 = d1 + 32;
      const float bv1 = bias[gcol0 + d1];
      const float bv2 = bias[gcol0 + d2];
#pragma unroll
      for (int rb = 0; rb < 2; ++rb) {
#pragma unroll
        for (int r = 0; r < 4; ++r) {
          const int n = nbase + wm * 32 + rb * 16 + quad * 4 + r;
          float v1 = acc[rb][cbp][r] + bv1;
          float v2 = acc[rb][cbp + 2][r] + bv2;
          float o1, o2;
          if (n < num_special) {
            o1 = v1; o2 = v2;
          } else {
            int ns = n - num_special;
            float c1 = cosT[ns * 64 + d1], s1 = sinT[ns * 64 + d1];
            float c2 = cosT[ns * 64 + d2], s2 = sinT[ns * 64 + d2];
            o1 = v1 * c1 - v2 * s1;
            o2 = v2 * c2 + v1 * s2;
          }
          size_t ob = ((size_t)bh * 2048 + n) * 64;
          outp[ob + d1] = f2bf(o1 * qs);
          outp[ob + d2] = f2bf(o2 * qs);
        }
      }
    }
  } else {
#pragma unroll
    for (int cb = 0; cb < 4; ++cb) {
      const int d = cb * 16 + l16;
      const float bv = bias[gcol0 + d];
#pragma unroll
      for (int rb = 0; rb < 2; ++rb) {
        const int nr = nbase + wm * 32 + rb * 16 + quad * 4;
        U64v o;
        o.x = (uint32_t)f2bf(acc[rb][cb][0] + bv) |
              ((uint32_t)f2bf(acc[rb][cb][1] + bv) << 16);
        o.y = (uint32_t)f2bf(acc[rb][cb][2] + bv) |
              ((uint32_t)f2bf(acc[rb][cb][3] + bv) << 16);
        *(U64v*)&Vto[((size_t)bh * 64 + d) * 2048 + nr] = o;
      }
    }
  }
}

// ---------------- flash attention: pair-PV at K=32, 3-slot LDS, V stays in LDS -----
// (R10/R11 config, unchanged — best measured 77.8-82 us, no spill.)
__global__ __launch_bounds__(256, 3)
void attn(const u16* __restrict__ Q, const u16* __restrict__ Kg,
          const u16* __restrict__ Vt, u16* __restrict__ Out) {
  __shared__ u16 smem2[3 * 8192];    // 48 KB: 3 slots x [K 64x64 | V 64x64]
  __shared__ float invS[64];
  const int tid = threadIdx.x;
  const int wave = tid >> 6, lane = tid & 63;
  const int quad = lane >> 4, l16 = lane & 15;
  const int idx = blockIdx.x;
  const int bh = idx % 48, qt = idx / 48;
  const int b = bh / 12, h = bh % 12;
  const u16* Qb = Q + (size_t)bh * 2048 * 64;
  const u16* Kb = Kg + (size_t)bh * 2048 * 64;
  const u16* Vb = Vt + (size_t)bh * 64 * 2048;
  const int wkey0 = wave * 16;

  const int lrow = lane >> 3;
  const int lch  = (lane & 7) ^ (lrow & 7);
  const int r0a = wave * 8;
  const int r0b = 32 + wave * 8;
  const int ksrc_a = (r0a + lrow) * 64 + lch * 8;
  const int ksrc_b = (r0b + lrow) * 64 + lch * 8;
  const size_t vsrc_a = (size_t)(r0a + lrow) * 2048 + lch * 8;
  const size_t vsrc_b = (size_t)(r0b + lrow) * 2048 + lch * 8;

  const int krd = (wkey0 + l16) * 64 + ((quad ^ (l16 & 7)) << 3);
  int vrd[4];
#pragma unroll
  for (int db = 0; db < 4; ++db)
    vrd[db] = (db * 16 + l16) * 64 +
              ((((wave << 1) | (quad >> 1)) ^ (l16 & 7)) << 3) + (quad & 1) * 4;

#define STAGE_A(kt_, s_)                                                      \
  do {                                                                        \
    u16* Kd = smem2 + (s_) * 8192;                                            \
    u16* Vd = Kd + 4096;                                                      \
    const u16* Ksrc = Kb + (size_t)(kt_) * 4096;                              \
    const u16* Vsrc = Vb + (kt_) * 64;                                        \
    gld16(Ksrc + ksrc_a, Kd + r0a * 64);                                      \
    gld16(Ksrc + ksrc_b, Kd + r0b * 64);                                      \
    gld16(Vsrc + vsrc_a, Vd + r0a * 64);                                      \
    gld16(Vsrc + vsrc_b, Vd + r0b * 64);                                      \
  } while (0)

#define QK_TILE(Ksh_, pf_)                                                    \
  do {                                                                        \
    bf16x8 ka0_ = ldfrag((Ksh_) + krd);                                       \
    bf16x8 ka1_ = ldfrag((Ksh_) + (krd ^ 32));                                \
    _Pragma("unroll")                                                         \
    for (int m = 0; m < 4; ++m) {                                             \
      f32x4 st = (f32x4){0.f, 0.f, 0.f, 0.f};                                 \
      st = __builtin_amdgcn_mfma_f32_16x16x32_bf16(ka0_, qf[m][0], st, 0, 0, 0); \
      st = __builtin_amdgcn_mfma_f32_16x16x32_bf16(ka1_, qf[m][1], st, 0, 0, 0); \
      float p0 = EXP2(st[0]), p1 = EXP2(st[1]), p2 = EXP2(st[2]), p3 = EXP2(st[3]); \
      psum[m] += (p0 + p1) + (p2 + p3);                                       \
      U64v pd_; pd_.x = pkbf(p0, p1); pd_.y = pkbf(p2, p3);                   \
      (pf_)[m] = pd_;                                                         \
    }                                                                         \
  } while (0)

  bf16x8 qf[4][2];
#pragma unroll
  for (int m = 0; m < 4; ++m) {
    const u16* qp = Qb + (size_t)(qt * 64 + m * 16 + l16) * 64 + quad * 8;
    qf[m][0] = ldfrag(qp);
    qf[m][1] = ldfrag(qp + 32);
  }

  f32x4 oacc[4][4];
#pragma unroll
  for (int m = 0; m < 4; ++m)
#pragma unroll
    for (int db = 0; db < 4; ++db) oacc[m][db] = (f32x4){0.f, 0.f, 0.f, 0.f};
  float psum[4] = {0.f, 0.f, 0.f, 0.f};

  U64v pfE[4], pfO[4];

  STAGE_A(0, 0);
  STAGE_A(1, 1);
  __syncthreads();

  for (int j = 0; j < 16; ++j) {
    const int t0 = 2 * j;
    const int sE = t0 % 3;
    const int sO = (t0 + 1) % 3;
    if (t0 >= 2) STAGE_A(t0 + 1, sO);
    if (t0 + 2 < 32) STAGE_A(t0 + 2, (t0 + 2) % 3);
    const u16* KshE = smem2 + sE * 8192;
    QK_TILE(KshE, pfE);
    __syncthreads();
    const u16* KshO = smem2 + sO * 8192;
    QK_TILE(KshO, pfO);
    bf16x8 pa0 = cat8(pfE[0], pfO[0]);
    bf16x8 pa1 = cat8(pfE[1], pfO[1]);
    bf16x8 pa2 = cat8(pfE[2], pfO[2]);
    bf16x8 pa3 = cat8(pfE[3], pfO[3]);
    const u16* VshE = KshE + 4096;
    const u16* VshO = KshO + 4096;
#pragma unroll
    for (int db = 0; db < 4; ++db) {
      U64v vlo = *(const U64v*)(VshE + vrd[db]);
      U64v vhi = *(const U64v*)(VshO + vrd[db]);
      bf16x8 vf8 = cat8(vlo, vhi);
      oacc[0][db] = __builtin_amdgcn_mfma_f32_16x16x32_bf16(pa0, vf8, oacc[0][db], 0, 0, 0);
      oacc[1][db] = __builtin_amdgcn_mfma_f32_16x16x32_bf16(pa1, vf8, oacc[1][db], 0, 0, 0);
      oacc[2][db] = __builtin_amdgcn_mfma_f32_16x16x32_bf16(pa2, vf8, oacc[2][db], 0, 0, 0);
      oacc[3][db] = __builtin_amdgcn_mfma_f32_16x16x32_bf16(pa3, vf8, oacc[3][db], 0, 0, 0);
    }
    __syncthreads();
  }
#undef STAGE_A
#undef QK_TILE

#pragma unroll
  for (int m = 0; m < 4; ++m) {
    psum[m] += __shfl_xor(psum[m], 16, 64);
    psum[m] += __shfl_xor(psum[m], 32, 64);
  }
  __syncthreads();
  float* LS = (float*)smem2;
  if (quad == 0) {
#pragma unroll
    for (int m = 0; m < 4; ++m) LS[wave * 64 + m * 16 + l16] = psum[m];
  }
  __syncthreads();
  if (tid < 64) {
    float tot = LS[tid] + LS[64 + tid] + LS[128 + tid] + LS[192 + tid];
    invS[tid] = 1.0f / tot;
  }

  float* OR = (float*)smem2;
  const int q = tid >> 2;
  const int d0 = (tid & 3) * 4;
  const size_t obase = ((size_t)(b * 2048 + qt * 64 + q)) * 768 + h * 64 + d0;
#pragma unroll
  for (int db = 0; db < 4; ++db) {
    __syncthreads();
#pragma unroll
    for (int m = 0; m < 4; ++m)
#pragma unroll
      for (int r = 0; r < 4; ++r)
        OR[(wave * 64 + m * 16 + quad * 4 + r) * 18 + l16] = oacc[m][db][r];
    __syncthreads();
    float s0 = 0.f, s1 = 0.f, s2 = 0.f, s3 = 0.f;
#pragma unroll
    for (int w = 0; w < 4; ++w) {
      const float* p = &OR[(w * 64 + q) * 18 + d0];
      s0 += p[0]; s1 += p[1]; s2 += p[2]; s3 += p[3];
    }
    float iv = invS[q];
    U64v o;
    o.x = (uint32_t)f2bf(s0 * iv) | ((uint32_t)f2bf(s1 * iv) << 16);
    o.y = (uint32_t)f2bf(s2 * iv) | ((uint32_t)f2bf(s3 * iv) << 16);
    *(U64v*)&Out[obase + db * 16] = o;
  }
}

extern "C" void kernel_launch(void* const* d_in, const int* in_sizes, int n_in,
                              void* d_out, int out_size, void* d_ws, size_t ws_size,
                              hipStream_t stream) {
  (void)in_sizes; (void)n_in; (void)out_size; (void)ws_size;
  const float* x        = (const float*)d_in[0];
  const float* rope_cos = (const float*)d_in[1];
  const float* rope_sin = (const float*)d_in[2];
  const float* W_qkv    = (const float*)d_in[3];
  const float* b_qkv    = (const float*)d_in[4];
  const float* W_proj   = (const float*)d_in[5];
  const float* b_proj   = (const float*)d_in[6];
  const int*   nsp      = (const int*)d_in[7];
  float* out = (float*)d_out;

  char* ws = (char*)d_ws;
  u16* Xb   = (u16*)(ws);              // 8192x768 bf16
  u16* Wqkt = (u16*)(ws + 12582912);   // 2304x768 bf16
  u16* Wpt  = (u16*)(ws + 16121856);   // 768x768 bf16
  u16* Qb   = (u16*)(ws + 55050240);   // 48x2048x64 bf16
  u16* Kb   = (u16*)(ws + 67633152);
  u16* Vtb  = (u16*)(ws + 80216064);   // 48x64x2048 bf16
  u16* att  = (u16*)(ws + 92798976);   // 8192x768 bf16

  prep<<<8448, 256, 0, stream>>>(x, Xb, W_qkv, Wqkt, W_proj, Wpt);
  gemm_qkv_rope<<<dim3(18, 64), 512, 0, stream>>>(Xb, Wqkt, b_qkv, rope_cos, rope_sin,
                                                  nsp, Qb, Kb, Vtb);
  attn<<<1536, 256, 0, stream>>>(Qb, Kb, Vtb, att);
  gemm_bt<<<dim3(6, 64), 512, 0, stream>>>(att, Wpt, b_proj, out, 8192, 768, 768);
}